// Round 11
// baseline (265.935 us; speedup 1.0000x reference)
//
#include <hip/hip_runtime.h>
#include <math.h>

// ---------------------------------------------------------------------------
// GraphSAGE 3-layer forward — R23: R21 structure (204.2us proven, unroll-4
//  aggs restored; R22 unroll-8 REVERTED: +6us, aggs are issue-bound not
//  latency-bound) + DIAGNOSTIC: each of the 5 layer kernels is dispatched
//  TWICE back-to-back (idempotent: identical inputs -> identical outputs).
//  T_new - 204.2 = sum(warm layer kernels) + 5 boundaries — the per-kernel
//  cost measurement the fill-occluded top-5 profile has never shown.
//  - R21: bucket_csr at 1024 threads/block.
//  - R19: heterogeneous {scatter ∥ transform1} fusion.
//  - transforms: MFMA bf16 GEMM; y1l/y2l fp8 e4m3 payloads, y3l bf16.
//  - R15/R16 CSR: src-quartile row order, packed 64-bit quartile histogram,
//    bucketbase fused into bscan via last-block sync.
// Assumes N <= 2^17, NBKT = ceil(N/512) <= 256.
// ---------------------------------------------------------------------------

typedef __attribute__((ext_vector_type(8))) short short8;
typedef __attribute__((ext_vector_type(4))) float floatx4;
typedef __attribute__((ext_vector_type(2))) float floatx2;

__device__ __forceinline__ unsigned short f2bf(float f) {   // RNE
    unsigned u = __float_as_uint(f);
    u += 0x7fffu + ((u >> 16) & 1u);
    return (unsigned short)(u >> 16);
}
__device__ __forceinline__ float blo(unsigned u) { return __uint_as_float(u << 16); }
__device__ __forceinline__ float bhi(unsigned u) { return __uint_as_float(u & 0xffff0000u); }
__device__ __forceinline__ unsigned char f2fp8(float f) {   // e4m3fn via HW
    return (unsigned char)(__builtin_amdgcn_cvt_pk_fp8_f32(f, f, 0, false) & 0xFF);
}

// ---------------- CSR build (bucketed, atomic-free at global scope) ---------

__global__ __launch_bounds__(256) void hist_kernel(
        const int* __restrict__ ei, int* __restrict__ bh, int* __restrict__ sync_ctr,
        int E, int NB, int NBKT) {
    __shared__ int lh[256];
    const int tid = threadIdx.x, blk = blockIdx.x;
    if (blk == 0 && tid == 0) *sync_ctr = 0;   // for bscan last-block sync
    lh[tid] = 0;
    __syncthreads();
    const int base = blk << 12;
#pragma unroll
    for (int i = 0; i < 16; ++i) {
        const int e = base + (i << 8) + tid;
        if (e < E) atomicAdd(&lh[min((int)(((unsigned)ei[E + e]) >> 9), NBKT - 1)], 1);
    }
    __syncthreads();
    if (tid < NBKT) bh[tid * NB + blk] = lh[tid];
}

// bucketbase fused in via last-block pattern (device-scope atomic+fence).
__global__ __launch_bounds__(256) void bscan_kernel(
        const int* __restrict__ bh, int* __restrict__ offs, int* __restrict__ btot,
        int* __restrict__ bucket_base, int* __restrict__ sync_ctr,
        int NB, int NBKT) {
    const int lane = threadIdx.x & 63;
    const int w = blockIdx.x * 4 + (threadIdx.x >> 6);
    if (w < NBKT) {
        int running = 0;
        for (int base = 0; base < NB; base += 64) {
            const int j = base + lane;
            const int v = (j < NB) ? bh[w * NB + j] : 0;
            int incl = v;
#pragma unroll
            for (int off = 1; off < 64; off <<= 1) {
                const int t = __shfl_up(incl, off);
                if (lane >= off) incl += t;
            }
            if (j < NB) offs[w * NB + j] = running + incl - v;
            running += __shfl(incl, 63);
        }
        if (lane == 0) btot[w] = running;
    }
    __threadfence();                 // release btot/offs to device scope
    __syncthreads();
    __shared__ int amLast;
    if (threadIdx.x == 0) amLast = (atomicAdd(sync_ctr, 1) == (int)gridDim.x - 1);
    __syncthreads();
    if (amLast && threadIdx.x < 64) {
        __threadfence();             // acquire: other blocks' btot now visible
        int running = 0;
        for (int base = 0; base < NBKT; base += 64) {
            const int j = base + threadIdx.x;
            const int v = (j < NBKT) ? btot[j] : 0;
            int incl = v;
#pragma unroll
            for (int off = 1; off < 64; off <<= 1) {
                const int t = __shfl_up(incl, off);
                if ((int)threadIdx.x >= off) incl += t;
            }
            if (j < NBKT) bucket_base[j] = running + incl - v;
            running += __shfl(incl, 63);
        }
        if (threadIdx.x == 0) bucket_base[NBKT] = running;
    }
}

// ---- R19: heterogeneous fusion — blocks [0,NB) scatter, rest transform1 ----
template <int K, int F_OUT, int PAD, bool AFP32, bool YL8>
__global__ __launch_bounds__(256) void scatter_t1_kernel(
        const int* __restrict__ ei, const int* __restrict__ offs,
        const int* __restrict__ bucket_base, unsigned* __restrict__ ebuf,
        int E, int NB, int NBKT,
        const void* __restrict__ Ain, const float* __restrict__ Wl,
        const float* __restrict__ Wr, const float* __restrict__ b,
        void* __restrict__ yl, unsigned short* __restrict__ yr, int n) {
    __shared__ int lcur[256];
    const int tid = threadIdx.x;
    if ((int)blockIdx.x < NB) {
        // ---------------- scatter path ----------------
        const int blk = blockIdx.x;
        if (tid < NBKT) lcur[tid] = bucket_base[tid] + offs[tid * NB + blk];
        __syncthreads();
        const int base = blk << 12;
#pragma unroll
        for (int i = 0; i < 16; ++i) {
            const int e = base + (i << 8) + tid;
            if (e < E) {
                const int s = ei[e];
                const unsigned d = (unsigned)ei[E + e];
                int p = atomicAdd(&lcur[min((int)(d >> 9), NBKT - 1)], 1);
                p = min(p, E - 1);                       // defensive
                ebuf[p] = ((d & 511u) << 17) | (unsigned)s;
            }
        }
        return;
    }
    // ---------------- transform1 path ----------------
    constexpr int KSTEP = K / 32;
    constexpr int NT = PAD / 16;
    const int lane = tid & 63;
    const int wid = (((int)blockIdx.x - NB) * 256 + tid) >> 6;
    const int ntiles = (n + 15) >> 4;
    if (wid >= ntiles) return;
    const int nl = lane & 15, q = lane >> 4;

    short8 Bl[NT][KSTEP], Br[NT][KSTEP];
    float biasv[NT];
#pragma unroll
    for (int t = 0; t < NT; ++t) {
        const int ncol = t * 16 + nl;
        biasv[t] = (ncol < F_OUT) ? b[ncol] : 0.f;
#pragma unroll
        for (int ks = 0; ks < KSTEP; ++ks) {
#pragma unroll
            for (int j = 0; j < 8; ++j) {
                const int k = ks * 32 + q * 8 + j;
                Bl[t][ks][j] = (ncol < F_OUT) ? (short)f2bf(Wl[k * F_OUT + ncol]) : (short)0;
                Br[t][ks][j] = (ncol < F_OUT) ? (short)f2bf(Wr[k * F_OUT + ncol]) : (short)0;
            }
        }
    }

    const int m0 = wid * 16;
    int m = m0 + nl; if (m >= n) m = n - 1;

    short8 a[KSTEP];
#pragma unroll
    for (int ks = 0; ks < KSTEP; ++ks) {
        if (AFP32) {
            const float* p = (const float*)Ain + (size_t)m * K + ks * 32 + q * 8;
#pragma unroll
            for (int j = 0; j < 8; ++j) a[ks][j] = (short)f2bf(p[j]);
        } else {
            union { uint4 u; short8 s; } cvt;
            cvt.u = *(const uint4*)((const unsigned short*)Ain + (size_t)m * K + ks * 32 + q * 8);
            a[ks] = cvt.s;
        }
    }

    floatx4 accl[NT], accr[NT];
#pragma unroll
    for (int t = 0; t < NT; ++t) { accl[t] = {0.f,0.f,0.f,0.f}; accr[t] = {0.f,0.f,0.f,0.f}; }
#pragma unroll
    for (int ks = 0; ks < KSTEP; ++ks) {
#pragma unroll
        for (int t = 0; t < NT; ++t) {
            accl[t] = __builtin_amdgcn_mfma_f32_16x16x32_bf16(a[ks], Bl[t][ks], accl[t], 0, 0, 0);
            accr[t] = __builtin_amdgcn_mfma_f32_16x16x32_bf16(a[ks], Br[t][ks], accr[t], 0, 0, 0);
        }
    }

#pragma unroll
    for (int t = 0; t < NT; ++t) {
        const int ncol = t * 16 + nl;
#pragma unroll
        for (int r = 0; r < 4; ++r) {
            const int node = m0 + q * 4 + r;
            if (node < n) {
                if (YL8)
                    ((unsigned char*)yl)[(size_t)node * PAD + ncol] = f2fp8(accl[t][r]);
                else
                    ((unsigned short*)yl)[(size_t)node * PAD + ncol] = f2bf(accl[t][r]);
                yr[(size_t)node * PAD + ncol] = f2bf(accr[t][r] + biasv[t]);
            }
        }
    }
}

// R21: 1024 threads/block (2x sweep parallelism); scan confined to tid<512.
// Four-cursor src-quartile ordering; pass-1 histogram = ONE packed 64-bit LDS
// atomic per edge (16 bits per quartile); wave-shfl scan.
__global__ __launch_bounds__(1024) void bucket_csr_kernel(
        const unsigned* __restrict__ ebuf, const int* __restrict__ bucket_base,
        int* __restrict__ rowptr, int* __restrict__ deg, int* __restrict__ col,
        int N, int E) {
    __shared__ unsigned long long lcnt[512];
    __shared__ int lcur[2048]; // 4 cursors x 512 nodes
    __shared__ int wsum[8];
    const int b = blockIdx.x, tid = threadIdx.x;
    const int q1 = N >> 2, q2 = N >> 1, q3 = (N >> 2) + (N >> 1);
    const int segbase = bucket_base[b];
    const int L = bucket_base[b + 1] - segbase;
    if (tid < 512) lcnt[tid] = 0ull;
    __syncthreads();
    for (int i = tid; i < L; i += 1024) {
        const unsigned p = ebuf[segbase + i];
        const int ln = p >> 17;
        const int s  = (int)(p & 0x1FFFFu);
        const int q  = (s < q2) ? ((s < q1) ? 0 : 1) : ((s < q3) ? 2 : 3);
        atomicAdd(&lcnt[ln], 1ull << (q << 4));
    }
    __syncthreads();
    const unsigned long long cv = (tid < 512) ? lcnt[tid] : 0ull;
    const int f0 = (int)(cv & 0xFFFFu),         f1 = (int)((cv >> 16) & 0xFFFFu);
    const int f2 = (int)((cv >> 32) & 0xFFFFu), f3 = (int)((cv >> 48) & 0xFFFFu);
    const int dnode = f0 + f1 + f2 + f3;
    // block exclusive scan of dnode over tid<512: per-wave shfl + combine
    const int lane = tid & 63, w = tid >> 6;   // w in 0..15; scan uses w<8
    int incl = dnode;
#pragma unroll
    for (int off = 1; off < 64; off <<= 1) {
        const int t = __shfl_up(incl, off);
        if (lane >= off) incl += t;
    }
    if (lane == 63 && w < 8) wsum[w] = incl;
    __syncthreads();
    if (tid < 512) {
        int wbase = 0;
#pragma unroll
        for (int ww = 0; ww < 8; ++ww) if (ww < w) wbase += wsum[ww];
        const int excl = wbase + incl - dnode;
        const int node = (b << 9) + tid;
        if (node < N) { rowptr[node] = segbase + excl; deg[node] = dnode; }
        lcur[tid]        = excl;
        lcur[512 + tid]  = excl + f0;
        lcur[1024 + tid] = excl + f0 + f1;
        lcur[1536 + tid] = excl + f0 + f1 + f2;
    }
    __syncthreads();
    for (int i = tid; i < L; i += 1024) {
        const unsigned p = ebuf[segbase + i];
        const int ln = p >> 17;
        const int s  = (int)(p & 0x1FFFFu);
        const int q  = (s < q2) ? ((s < q1) ? 0 : 1) : ((s < q3) ? 2 : 3);
        int pos = atomicAdd(&lcur[(q << 9) + ln], 1);
        pos = min(segbase + pos, E - 1);             // defensive
        col[pos] = s;
    }
}

// ---------------- MFMA transform: y_l = A@Wl (fp8|bf16), y_r = A@Wr+b (bf16) -
template <int K, int F_OUT, int PAD, bool AFP32, bool YL8>
__global__ __launch_bounds__(256) void transform_kernel(
        const void* __restrict__ Ain, const float* __restrict__ Wl,
        const float* __restrict__ Wr, const float* __restrict__ b,
        void* __restrict__ yl, unsigned short* __restrict__ yr, int n) {
    constexpr int KSTEP = K / 32;
    constexpr int NT = PAD / 16;
    const int lane = threadIdx.x & 63;
    const int wid = (blockIdx.x * blockDim.x + threadIdx.x) >> 6;
    const int ntiles = (n + 15) >> 4;
    if (wid >= ntiles) return;
    const int nl = lane & 15, q = lane >> 4;

    short8 Bl[NT][KSTEP], Br[NT][KSTEP];
    float biasv[NT];
#pragma unroll
    for (int t = 0; t < NT; ++t) {
        const int ncol = t * 16 + nl;
        biasv[t] = (ncol < F_OUT) ? b[ncol] : 0.f;
#pragma unroll
        for (int ks = 0; ks < KSTEP; ++ks) {
#pragma unroll
            for (int j = 0; j < 8; ++j) {
                const int k = ks * 32 + q * 8 + j;
                Bl[t][ks][j] = (ncol < F_OUT) ? (short)f2bf(Wl[k * F_OUT + ncol]) : (short)0;
                Br[t][ks][j] = (ncol < F_OUT) ? (short)f2bf(Wr[k * F_OUT + ncol]) : (short)0;
            }
        }
    }

    const int m0 = wid * 16;
    int m = m0 + nl; if (m >= n) m = n - 1;

    short8 a[KSTEP];
#pragma unroll
    for (int ks = 0; ks < KSTEP; ++ks) {
        if (AFP32) {
            const float* p = (const float*)Ain + (size_t)m * K + ks * 32 + q * 8;
#pragma unroll
            for (int j = 0; j < 8; ++j) a[ks][j] = (short)f2bf(p[j]);
        } else {
            union { uint4 u; short8 s; } cvt;
            cvt.u = *(const uint4*)((const unsigned short*)Ain + (size_t)m * K + ks * 32 + q * 8);
            a[ks] = cvt.s;
        }
    }

    floatx4 accl[NT], accr[NT];
#pragma unroll
    for (int t = 0; t < NT; ++t) { accl[t] = {0.f,0.f,0.f,0.f}; accr[t] = {0.f,0.f,0.f,0.f}; }
#pragma unroll
    for (int ks = 0; ks < KSTEP; ++ks) {
#pragma unroll
        for (int t = 0; t < NT; ++t) {
            accl[t] = __builtin_amdgcn_mfma_f32_16x16x32_bf16(a[ks], Bl[t][ks], accl[t], 0, 0, 0);
            accr[t] = __builtin_amdgcn_mfma_f32_16x16x32_bf16(a[ks], Br[t][ks], accr[t], 0, 0, 0);
        }
    }

#pragma unroll
    for (int t = 0; t < NT; ++t) {
        const int ncol = t * 16 + nl;
#pragma unroll
        for (int r = 0; r < 4; ++r) {
            const int node = m0 + q * 4 + r;
            if (node < n) {
                if (YL8)
                    ((unsigned char*)yl)[(size_t)node * PAD + ncol] = f2fp8(accl[t][r]);
                else
                    ((unsigned short*)yl)[(size_t)node * PAD + ncol] = f2bf(accl[t][r]);
                yr[(size_t)node * PAD + ncol] = f2bf(accr[t][r] + biasv[t]);
            }
        }
    }
}

// ---------------- aggregate: h = act(norm(mean_gather(yl) + yr)) ------------
// R16: software-pipelined col prefetch — next quad's col indices load while
// current quad's payload gathers are outstanding (8 loads in flight).
// PK: 0 = bf16 payload (uint4/row-chunk), 1 = fp8 payload (uint2/row-chunk).
template <int F, int ACT, int PK>
__global__ __launch_bounds__(256) void agg_kernel(
        const void* __restrict__ yl, const unsigned short* __restrict__ yr,
        const int* __restrict__ rowptr, const int* __restrict__ degv,
        const int* __restrict__ col,
        unsigned short* __restrict__ hout, float* __restrict__ fout, int n) {
    constexpr int G = F / 8;
    constexpr int NPW = 64 / G;
    const int lane = threadIdx.x & 63;
    const int wid = (blockIdx.x * blockDim.x + threadIdx.x) >> 6;
    const int g = lane / G, c = lane % G;
    const int node = wid * NPW + g;
    if (node >= n) return;

    const int beg = rowptr[node];
    const int dg  = degv[node];
    const int nmax = n - 1;

    float a0=0.f,a1=0.f,a2=0.f,a3=0.f,a4=0.f,a5=0.f,a6=0.f,a7=0.f;
    int i = 0;
    if (PK == 1) {
        const unsigned char* base = (const unsigned char*)yl + c * 8;
        auto accrow = [&](uint2 t) {
            const floatx2 p0 = __builtin_amdgcn_cvt_pk_f32_fp8((int)t.x, false);
            const floatx2 p1 = __builtin_amdgcn_cvt_pk_f32_fp8((int)t.x, true);
            const floatx2 p2 = __builtin_amdgcn_cvt_pk_f32_fp8((int)t.y, false);
            const floatx2 p3 = __builtin_amdgcn_cvt_pk_f32_fp8((int)t.y, true);
            a0 += p0.x; a1 += p0.y; a2 += p1.x; a3 += p1.y;
            a4 += p2.x; a5 += p2.y; a6 += p3.x; a7 += p3.y;
        };
        if (dg >= 4) {
            int c0 = col[beg], c1 = col[beg+1], c2 = col[beg+2], c3 = col[beg+3];
            for (; i + 8 <= dg; i += 4) {
                const int d0 = col[beg+i+4], d1 = col[beg+i+5];
                const int d2 = col[beg+i+6], d3 = col[beg+i+7];
                const uint2 t0 = *(const uint2*)(base + (size_t)min(c0,nmax) * F);
                const uint2 t1 = *(const uint2*)(base + (size_t)min(c1,nmax) * F);
                const uint2 t2 = *(const uint2*)(base + (size_t)min(c2,nmax) * F);
                const uint2 t3 = *(const uint2*)(base + (size_t)min(c3,nmax) * F);
                accrow(t0); accrow(t1); accrow(t2); accrow(t3);
                c0 = d0; c1 = d1; c2 = d2; c3 = d3;
            }
            const uint2 t0 = *(const uint2*)(base + (size_t)min(c0,nmax) * F);
            const uint2 t1 = *(const uint2*)(base + (size_t)min(c1,nmax) * F);
            const uint2 t2 = *(const uint2*)(base + (size_t)min(c2,nmax) * F);
            const uint2 t3 = *(const uint2*)(base + (size_t)min(c3,nmax) * F);
            accrow(t0); accrow(t1); accrow(t2); accrow(t3);
            i += 4;
        }
        for (; i < dg; ++i)
            accrow(*(const uint2*)(base + (size_t)min(col[beg+i],nmax) * F));
    } else {
        const unsigned short* base = (const unsigned short*)yl + c * 8;
        auto accrow4 = [&](uint4 t) {
            a0 += blo(t.x); a1 += bhi(t.x); a2 += blo(t.y); a3 += bhi(t.y);
            a4 += blo(t.z); a5 += bhi(t.z); a6 += blo(t.w); a7 += bhi(t.w);
        };
        if (dg >= 4) {
            int c0 = col[beg], c1 = col[beg+1], c2 = col[beg+2], c3 = col[beg+3];
            for (; i + 8 <= dg; i += 4) {
                const int d0 = col[beg+i+4], d1 = col[beg+i+5];
                const int d2 = col[beg+i+6], d3 = col[beg+i+7];
                const uint4 t0 = *(const uint4*)(base + (size_t)min(c0,nmax) * F);
                const uint4 t1 = *(const uint4*)(base + (size_t)min(c1,nmax) * F);
                const uint4 t2 = *(const uint4*)(base + (size_t)min(c2,nmax) * F);
                const uint4 t3 = *(const uint4*)(base + (size_t)min(c3,nmax) * F);
                accrow4(t0); accrow4(t1); accrow4(t2); accrow4(t3);
                c0 = d0; c1 = d1; c2 = d2; c3 = d3;
            }
            const uint4 t0 = *(const uint4*)(base + (size_t)min(c0,nmax) * F);
            const uint4 t1 = *(const uint4*)(base + (size_t)min(c1,nmax) * F);
            const uint4 t2 = *(const uint4*)(base + (size_t)min(c2,nmax) * F);
            const uint4 t3 = *(const uint4*)(base + (size_t)min(c3,nmax) * F);
            accrow4(t0); accrow4(t1); accrow4(t2); accrow4(t3);
            i += 4;
        }
        for (; i < dg; ++i)
            accrow4(*(const uint4*)(base + (size_t)min(col[beg+i],nmax) * F));
    }
    const float inv = (dg > 0) ? 1.f / (float)dg : 0.f;

    // yr residual: bf16, coalesced
    const uint4 rv = *(const uint4*)(yr + (size_t)node * F + c * 8);
    float o[8];
    o[0] = a0*inv + blo(rv.x); o[1] = a1*inv + bhi(rv.x);
    o[2] = a2*inv + blo(rv.y); o[3] = a3*inv + bhi(rv.y);
    o[4] = a4*inv + blo(rv.z); o[5] = a5*inv + bhi(rv.z);
    o[6] = a6*inv + blo(rv.w); o[7] = a7*inv + bhi(rv.w);

    float ss = 0.f;
#pragma unroll
    for (int j = 0; j < 8; ++j) ss += o[j] * o[j];
#pragma unroll
    for (int off = 1; off < G; off <<= 1) ss += __shfl_xor(ss, off);
    const float scale = 1.f / fmaxf(sqrtf(ss), 1e-12f);

    if (ACT == 1) {
        uint4 u;
        float h[8];
#pragma unroll
        for (int j = 0; j < 8; ++j) h[j] = fmaxf(o[j] * scale, 0.f);
        u.x = (unsigned)f2bf(h[0]) | ((unsigned)f2bf(h[1]) << 16);
        u.y = (unsigned)f2bf(h[2]) | ((unsigned)f2bf(h[3]) << 16);
        u.z = (unsigned)f2bf(h[4]) | ((unsigned)f2bf(h[5]) << 16);
        u.w = (unsigned)f2bf(h[6]) | ((unsigned)f2bf(h[7]) << 16);
        *(uint4*)(hout + (size_t)node * F + c * 8) = u;
    } else {
#pragma unroll
        for (int j = 0; j < 8; ++j) o[j] *= scale;
        const int cbase = c * 8;
        float m = -INFINITY;
#pragma unroll
        for (int j = 0; j < 8; ++j) if (cbase + j < 10) m = fmaxf(m, o[j]);
        m = fmaxf(m, __shfl_xor(m, 1));
        float s = 0.f;
#pragma unroll
        for (int j = 0; j < 8; ++j) if (cbase + j < 10) s += __expf(o[j] - m);
        s += __shfl_xor(s, 1);
        const float ls = logf(s);
#pragma unroll
        for (int j = 0; j < 8; ++j)
            if (cbase + j < 10) fout[(size_t)node * 10 + cbase + j] = o[j] - m - ls;
    }
}

extern "C" void kernel_launch(void* const* d_in, const int* in_sizes, int n_in,
                              void* d_out, int out_size, void* d_ws, size_t ws_size,
                              hipStream_t stream) {
    const float* x   = (const float*)d_in[0];
    const int*   ei  = (const int*)d_in[1];     // int64 in ref -> int32 on device
    const float* W1l = (const float*)d_in[2];
    const float* W1r = (const float*)d_in[3];
    const float* b1  = (const float*)d_in[4];
    const float* W2l = (const float*)d_in[5];
    const float* W2r = (const float*)d_in[6];
    const float* b2  = (const float*)d_in[7];
    const float* W3l = (const float*)d_in[8];
    const float* W3r = (const float*)d_in[9];
    const float* b3  = (const float*)d_in[10];
    float*       out = (float*)d_out;

    const int N = in_sizes[0] / 64;
    const int E = in_sizes[1] / 2;
    const int NBKT = (N + 511) >> 9;     // dst buckets of 512 nodes (<=256)
    const int NB   = (E + 4095) >> 12;   // 4096 edges per hist/scatter block

    auto align16 = [](size_t v) { return (v + 15) & ~(size_t)15; };
    char* ws = (char*)d_ws;
    size_t off = 0;
    int* rowptr  = (int*)(ws + off); off = align16(off + (size_t)N * 4);
    int* deg     = (int*)(ws + off); off = align16(off + (size_t)N * 4);
    int* colidx  = (int*)(ws + off); off = align16(off + (size_t)E * 4);
    unsigned* ebuf = (unsigned*)(ws + off); off = align16(off + (size_t)E * 4);
    int* bh      = (int*)(ws + off); off = align16(off + (size_t)NBKT * NB * 4);
    int* offsb   = (int*)(ws + off); off = align16(off + (size_t)NBKT * NB * 4);
    int* btot    = (int*)(ws + off); off = align16(off + (size_t)NBKT * 4);
    int* bbase   = (int*)(ws + off); off = align16(off + (size_t)(NBKT + 1) * 4);
    int* sctr    = (int*)(ws + off); off = align16(off + 16);
    unsigned char*  y1l = (unsigned char*)(ws + off);  off = align16(off + (size_t)N * 64);
    unsigned short* y1r = (unsigned short*)(ws + off); off = align16(off + (size_t)N * 64 * 2);
    unsigned short* h1  = (unsigned short*)(ws + off); off = align16(off + (size_t)N * 64 * 2);
    unsigned char*  y2l = (unsigned char*)(ws + off);  off = align16(off + (size_t)N * 32);
    unsigned short* y2r = (unsigned short*)(ws + off); off = align16(off + (size_t)N * 32 * 2);
    unsigned short* h2  = (unsigned short*)(ws + off); off = align16(off + (size_t)N * 32 * 2);
    unsigned short* y3l = (unsigned short*)(ws + off); off = align16(off + (size_t)N * 16 * 2);
    unsigned short* y3r = (unsigned short*)(ws + off); off = align16(off + (size_t)N * 16 * 2);
    (void)ws_size; (void)n_in; (void)out_size;

    const int ntiles = (N + 15) / 16;                  // MFMA node tiles
    const int tblocks = (ntiles * 64 + 255) / 256;     // 4 waves/block (t1)

    // ---- CSR build; transform1 overlapped with scatter (independent work)
    hist_kernel<<<NB, 256, 0, stream>>>(ei, bh, sctr, E, NB, NBKT);
    bscan_kernel<<<(NBKT + 3) / 4, 256, 0, stream>>>(bh, offsb, btot, bbase, sctr, NB, NBKT);
    scatter_t1_kernel<64, 64, 64, true, true><<<NB + tblocks, 256, 0, stream>>>(
        ei, offsb, bbase, ebuf, E, NB, NBKT,
        x, W1l, W1r, b1, y1l, y1r, N);
    bucket_csr_kernel<<<NBKT, 1024, 0, stream>>>(ebuf, bbase, rowptr, deg, colidx, N, E);

    // ---- DIAGNOSTIC (R23): each layer kernel dispatched twice back-to-back.
    // Idempotent -> bit-identical output; T - 204.2 = sum(warm kernels) + 5b.
    // layer 1 (fp8 gather payload)
    agg_kernel<64, 1, 1><<<(N + 31) / 32, 256, 0, stream>>>(
        y1l, y1r, rowptr, deg, colidx, h1, nullptr, N);
    agg_kernel<64, 1, 1><<<(N + 31) / 32, 256, 0, stream>>>(
        y1l, y1r, rowptr, deg, colidx, h1, nullptr, N);
    // layer 2 (fp8 gather payload)
    transform_kernel<64, 32, 32, false, true><<<tblocks, 256, 0, stream>>>(
        h1, W2l, W2r, b2, y2l, y2r, N);
    transform_kernel<64, 32, 32, false, true><<<tblocks, 256, 0, stream>>>(
        h1, W2l, W2r, b2, y2l, y2r, N);
    agg_kernel<32, 1, 1><<<(N + 63) / 64, 256, 0, stream>>>(
        y2l, y2r, rowptr, deg, colidx, h2, nullptr, N);
    agg_kernel<32, 1, 1><<<(N + 63) / 64, 256, 0, stream>>>(
        y2l, y2r, rowptr, deg, colidx, h2, nullptr, N);
    // layer 3 (bf16 payload, L2-resident)
    transform_kernel<32, 10, 16, false, false><<<tblocks, 256, 0, stream>>>(
        h2, W3l, W3r, b3, y3l, y3r, N);
    transform_kernel<32, 10, 16, false, false><<<tblocks, 256, 0, stream>>>(
        h2, W3l, W3r, b3, y3l, y3r, N);
    agg_kernel<16, 2, 0><<<(N + 127) / 128, 256, 0, stream>>>(
        y3l, y3r, rowptr, deg, colidx, nullptr, out, N);
    agg_kernel<16, 2, 0><<<(N + 127) / 128, 256, 0, stream>>>(
        y3l, y3r, rowptr, deg, colidx, nullptr, out, N);
}

// Round 12
// 203.978 us; speedup vs baseline: 1.3037x; 1.3037x over previous
//
#include <hip/hip_runtime.h>
#include <math.h>

// ---------------------------------------------------------------------------
// GraphSAGE 3-layer forward — R24: FINAL = R21 restored (204.2us proven).
//  R23 diagnostic (each layer kernel x2) measured Delta=61.7us for 5 warm
//  kernels + 5 boundaries -> warm layer kernels ~20us total, boundary ~8us.
//  Budget: 204 = ~95 harness-fixed (poison fill + graph overhead) + ~50
//  boundaries (8 dispatches) + ~60 kernel work. No HW roofline in play;
//  all structural boundary-removal attacks measured worse:
//   R17/R18 persistent mega-kernel: 3x worse (device-barrier spin pathology)
//   R20 dependent agg+transform fusion: +6.5us (VGPR/occupancy tax on gather)
//   R14 edge-parallel agg: +37us (destroyed phase locality, FETCH 72MB)
//   R22 unroll-8 agg: +6us (aggs are issue-bound, not latency-bound)
//  Banked wins: R19 {scatter ∥ transform1} heterogeneous fusion (-5.6),
//  R21 bucket_csr 1024 threads (-2.5), R16 packed histogram + col prefetch,
//  R15 src-quartile row order (locality), fp8 payloads (R11/R12).
// Assumes N <= 2^17, NBKT = ceil(N/512) <= 256.
// ---------------------------------------------------------------------------

typedef __attribute__((ext_vector_type(8))) short short8;
typedef __attribute__((ext_vector_type(4))) float floatx4;
typedef __attribute__((ext_vector_type(2))) float floatx2;

__device__ __forceinline__ unsigned short f2bf(float f) {   // RNE
    unsigned u = __float_as_uint(f);
    u += 0x7fffu + ((u >> 16) & 1u);
    return (unsigned short)(u >> 16);
}
__device__ __forceinline__ float blo(unsigned u) { return __uint_as_float(u << 16); }
__device__ __forceinline__ float bhi(unsigned u) { return __uint_as_float(u & 0xffff0000u); }
__device__ __forceinline__ unsigned char f2fp8(float f) {   // e4m3fn via HW
    return (unsigned char)(__builtin_amdgcn_cvt_pk_fp8_f32(f, f, 0, false) & 0xFF);
}

// ---------------- CSR build (bucketed, atomic-free at global scope) ---------

__global__ __launch_bounds__(256) void hist_kernel(
        const int* __restrict__ ei, int* __restrict__ bh, int* __restrict__ sync_ctr,
        int E, int NB, int NBKT) {
    __shared__ int lh[256];
    const int tid = threadIdx.x, blk = blockIdx.x;
    if (blk == 0 && tid == 0) *sync_ctr = 0;   // for bscan last-block sync
    lh[tid] = 0;
    __syncthreads();
    const int base = blk << 12;
#pragma unroll
    for (int i = 0; i < 16; ++i) {
        const int e = base + (i << 8) + tid;
        if (e < E) atomicAdd(&lh[min((int)(((unsigned)ei[E + e]) >> 9), NBKT - 1)], 1);
    }
    __syncthreads();
    if (tid < NBKT) bh[tid * NB + blk] = lh[tid];
}

// bucketbase fused in via last-block pattern (device-scope atomic+fence).
__global__ __launch_bounds__(256) void bscan_kernel(
        const int* __restrict__ bh, int* __restrict__ offs, int* __restrict__ btot,
        int* __restrict__ bucket_base, int* __restrict__ sync_ctr,
        int NB, int NBKT) {
    const int lane = threadIdx.x & 63;
    const int w = blockIdx.x * 4 + (threadIdx.x >> 6);
    if (w < NBKT) {
        int running = 0;
        for (int base = 0; base < NB; base += 64) {
            const int j = base + lane;
            const int v = (j < NB) ? bh[w * NB + j] : 0;
            int incl = v;
#pragma unroll
            for (int off = 1; off < 64; off <<= 1) {
                const int t = __shfl_up(incl, off);
                if (lane >= off) incl += t;
            }
            if (j < NB) offs[w * NB + j] = running + incl - v;
            running += __shfl(incl, 63);
        }
        if (lane == 0) btot[w] = running;
    }
    __threadfence();                 // release btot/offs to device scope
    __syncthreads();
    __shared__ int amLast;
    if (threadIdx.x == 0) amLast = (atomicAdd(sync_ctr, 1) == (int)gridDim.x - 1);
    __syncthreads();
    if (amLast && threadIdx.x < 64) {
        __threadfence();             // acquire: other blocks' btot now visible
        int running = 0;
        for (int base = 0; base < NBKT; base += 64) {
            const int j = base + threadIdx.x;
            const int v = (j < NBKT) ? btot[j] : 0;
            int incl = v;
#pragma unroll
            for (int off = 1; off < 64; off <<= 1) {
                const int t = __shfl_up(incl, off);
                if ((int)threadIdx.x >= off) incl += t;
            }
            if (j < NBKT) bucket_base[j] = running + incl - v;
            running += __shfl(incl, 63);
        }
        if (threadIdx.x == 0) bucket_base[NBKT] = running;
    }
}

// ---- R19: heterogeneous fusion — blocks [0,NB) scatter, rest transform1 ----
template <int K, int F_OUT, int PAD, bool AFP32, bool YL8>
__global__ __launch_bounds__(256) void scatter_t1_kernel(
        const int* __restrict__ ei, const int* __restrict__ offs,
        const int* __restrict__ bucket_base, unsigned* __restrict__ ebuf,
        int E, int NB, int NBKT,
        const void* __restrict__ Ain, const float* __restrict__ Wl,
        const float* __restrict__ Wr, const float* __restrict__ b,
        void* __restrict__ yl, unsigned short* __restrict__ yr, int n) {
    __shared__ int lcur[256];
    const int tid = threadIdx.x;
    if ((int)blockIdx.x < NB) {
        // ---------------- scatter path ----------------
        const int blk = blockIdx.x;
        if (tid < NBKT) lcur[tid] = bucket_base[tid] + offs[tid * NB + blk];
        __syncthreads();
        const int base = blk << 12;
#pragma unroll
        for (int i = 0; i < 16; ++i) {
            const int e = base + (i << 8) + tid;
            if (e < E) {
                const int s = ei[e];
                const unsigned d = (unsigned)ei[E + e];
                int p = atomicAdd(&lcur[min((int)(d >> 9), NBKT - 1)], 1);
                p = min(p, E - 1);                       // defensive
                ebuf[p] = ((d & 511u) << 17) | (unsigned)s;
            }
        }
        return;
    }
    // ---------------- transform1 path ----------------
    constexpr int KSTEP = K / 32;
    constexpr int NT = PAD / 16;
    const int lane = tid & 63;
    const int wid = (((int)blockIdx.x - NB) * 256 + tid) >> 6;
    const int ntiles = (n + 15) >> 4;
    if (wid >= ntiles) return;
    const int nl = lane & 15, q = lane >> 4;

    short8 Bl[NT][KSTEP], Br[NT][KSTEP];
    float biasv[NT];
#pragma unroll
    for (int t = 0; t < NT; ++t) {
        const int ncol = t * 16 + nl;
        biasv[t] = (ncol < F_OUT) ? b[ncol] : 0.f;
#pragma unroll
        for (int ks = 0; ks < KSTEP; ++ks) {
#pragma unroll
            for (int j = 0; j < 8; ++j) {
                const int k = ks * 32 + q * 8 + j;
                Bl[t][ks][j] = (ncol < F_OUT) ? (short)f2bf(Wl[k * F_OUT + ncol]) : (short)0;
                Br[t][ks][j] = (ncol < F_OUT) ? (short)f2bf(Wr[k * F_OUT + ncol]) : (short)0;
            }
        }
    }

    const int m0 = wid * 16;
    int m = m0 + nl; if (m >= n) m = n - 1;

    short8 a[KSTEP];
#pragma unroll
    for (int ks = 0; ks < KSTEP; ++ks) {
        if (AFP32) {
            const float* p = (const float*)Ain + (size_t)m * K + ks * 32 + q * 8;
#pragma unroll
            for (int j = 0; j < 8; ++j) a[ks][j] = (short)f2bf(p[j]);
        } else {
            union { uint4 u; short8 s; } cvt;
            cvt.u = *(const uint4*)((const unsigned short*)Ain + (size_t)m * K + ks * 32 + q * 8);
            a[ks] = cvt.s;
        }
    }

    floatx4 accl[NT], accr[NT];
#pragma unroll
    for (int t = 0; t < NT; ++t) { accl[t] = {0.f,0.f,0.f,0.f}; accr[t] = {0.f,0.f,0.f,0.f}; }
#pragma unroll
    for (int ks = 0; ks < KSTEP; ++ks) {
#pragma unroll
        for (int t = 0; t < NT; ++t) {
            accl[t] = __builtin_amdgcn_mfma_f32_16x16x32_bf16(a[ks], Bl[t][ks], accl[t], 0, 0, 0);
            accr[t] = __builtin_amdgcn_mfma_f32_16x16x32_bf16(a[ks], Br[t][ks], accr[t], 0, 0, 0);
        }
    }

#pragma unroll
    for (int t = 0; t < NT; ++t) {
        const int ncol = t * 16 + nl;
#pragma unroll
        for (int r = 0; r < 4; ++r) {
            const int node = m0 + q * 4 + r;
            if (node < n) {
                if (YL8)
                    ((unsigned char*)yl)[(size_t)node * PAD + ncol] = f2fp8(accl[t][r]);
                else
                    ((unsigned short*)yl)[(size_t)node * PAD + ncol] = f2bf(accl[t][r]);
                yr[(size_t)node * PAD + ncol] = f2bf(accr[t][r] + biasv[t]);
            }
        }
    }
}

// R21: 1024 threads/block (2x sweep parallelism); scan confined to tid<512.
// Four-cursor src-quartile ordering; pass-1 histogram = ONE packed 64-bit LDS
// atomic per edge (16 bits per quartile); wave-shfl scan.
__global__ __launch_bounds__(1024) void bucket_csr_kernel(
        const unsigned* __restrict__ ebuf, const int* __restrict__ bucket_base,
        int* __restrict__ rowptr, int* __restrict__ deg, int* __restrict__ col,
        int N, int E) {
    __shared__ unsigned long long lcnt[512];
    __shared__ int lcur[2048]; // 4 cursors x 512 nodes
    __shared__ int wsum[8];
    const int b = blockIdx.x, tid = threadIdx.x;
    const int q1 = N >> 2, q2 = N >> 1, q3 = (N >> 2) + (N >> 1);
    const int segbase = bucket_base[b];
    const int L = bucket_base[b + 1] - segbase;
    if (tid < 512) lcnt[tid] = 0ull;
    __syncthreads();
    for (int i = tid; i < L; i += 1024) {
        const unsigned p = ebuf[segbase + i];
        const int ln = p >> 17;
        const int s  = (int)(p & 0x1FFFFu);
        const int q  = (s < q2) ? ((s < q1) ? 0 : 1) : ((s < q3) ? 2 : 3);
        atomicAdd(&lcnt[ln], 1ull << (q << 4));
    }
    __syncthreads();
    const unsigned long long cv = (tid < 512) ? lcnt[tid] : 0ull;
    const int f0 = (int)(cv & 0xFFFFu),         f1 = (int)((cv >> 16) & 0xFFFFu);
    const int f2 = (int)((cv >> 32) & 0xFFFFu), f3 = (int)((cv >> 48) & 0xFFFFu);
    const int dnode = f0 + f1 + f2 + f3;
    // block exclusive scan of dnode over tid<512: per-wave shfl + combine
    const int lane = tid & 63, w = tid >> 6;   // w in 0..15; scan uses w<8
    int incl = dnode;
#pragma unroll
    for (int off = 1; off < 64; off <<= 1) {
        const int t = __shfl_up(incl, off);
        if (lane >= off) incl += t;
    }
    if (lane == 63 && w < 8) wsum[w] = incl;
    __syncthreads();
    if (tid < 512) {
        int wbase = 0;
#pragma unroll
        for (int ww = 0; ww < 8; ++ww) if (ww < w) wbase += wsum[ww];
        const int excl = wbase + incl - dnode;
        const int node = (b << 9) + tid;
        if (node < N) { rowptr[node] = segbase + excl; deg[node] = dnode; }
        lcur[tid]        = excl;
        lcur[512 + tid]  = excl + f0;
        lcur[1024 + tid] = excl + f0 + f1;
        lcur[1536 + tid] = excl + f0 + f1 + f2;
    }
    __syncthreads();
    for (int i = tid; i < L; i += 1024) {
        const unsigned p = ebuf[segbase + i];
        const int ln = p >> 17;
        const int s  = (int)(p & 0x1FFFFu);
        const int q  = (s < q2) ? ((s < q1) ? 0 : 1) : ((s < q3) ? 2 : 3);
        int pos = atomicAdd(&lcur[(q << 9) + ln], 1);
        pos = min(segbase + pos, E - 1);             // defensive
        col[pos] = s;
    }
}

// ---------------- MFMA transform: y_l = A@Wl (fp8|bf16), y_r = A@Wr+b (bf16) -
template <int K, int F_OUT, int PAD, bool AFP32, bool YL8>
__global__ __launch_bounds__(256) void transform_kernel(
        const void* __restrict__ Ain, const float* __restrict__ Wl,
        const float* __restrict__ Wr, const float* __restrict__ b,
        void* __restrict__ yl, unsigned short* __restrict__ yr, int n) {
    constexpr int KSTEP = K / 32;
    constexpr int NT = PAD / 16;
    const int lane = threadIdx.x & 63;
    const int wid = (blockIdx.x * blockDim.x + threadIdx.x) >> 6;
    const int ntiles = (n + 15) >> 4;
    if (wid >= ntiles) return;
    const int nl = lane & 15, q = lane >> 4;

    short8 Bl[NT][KSTEP], Br[NT][KSTEP];
    float biasv[NT];
#pragma unroll
    for (int t = 0; t < NT; ++t) {
        const int ncol = t * 16 + nl;
        biasv[t] = (ncol < F_OUT) ? b[ncol] : 0.f;
#pragma unroll
        for (int ks = 0; ks < KSTEP; ++ks) {
#pragma unroll
            for (int j = 0; j < 8; ++j) {
                const int k = ks * 32 + q * 8 + j;
                Bl[t][ks][j] = (ncol < F_OUT) ? (short)f2bf(Wl[k * F_OUT + ncol]) : (short)0;
                Br[t][ks][j] = (ncol < F_OUT) ? (short)f2bf(Wr[k * F_OUT + ncol]) : (short)0;
            }
        }
    }

    const int m0 = wid * 16;
    int m = m0 + nl; if (m >= n) m = n - 1;

    short8 a[KSTEP];
#pragma unroll
    for (int ks = 0; ks < KSTEP; ++ks) {
        if (AFP32) {
            const float* p = (const float*)Ain + (size_t)m * K + ks * 32 + q * 8;
#pragma unroll
            for (int j = 0; j < 8; ++j) a[ks][j] = (short)f2bf(p[j]);
        } else {
            union { uint4 u; short8 s; } cvt;
            cvt.u = *(const uint4*)((const unsigned short*)Ain + (size_t)m * K + ks * 32 + q * 8);
            a[ks] = cvt.s;
        }
    }

    floatx4 accl[NT], accr[NT];
#pragma unroll
    for (int t = 0; t < NT; ++t) { accl[t] = {0.f,0.f,0.f,0.f}; accr[t] = {0.f,0.f,0.f,0.f}; }
#pragma unroll
    for (int ks = 0; ks < KSTEP; ++ks) {
#pragma unroll
        for (int t = 0; t < NT; ++t) {
            accl[t] = __builtin_amdgcn_mfma_f32_16x16x32_bf16(a[ks], Bl[t][ks], accl[t], 0, 0, 0);
            accr[t] = __builtin_amdgcn_mfma_f32_16x16x32_bf16(a[ks], Br[t][ks], accr[t], 0, 0, 0);
        }
    }

#pragma unroll
    for (int t = 0; t < NT; ++t) {
        const int ncol = t * 16 + nl;
#pragma unroll
        for (int r = 0; r < 4; ++r) {
            const int node = m0 + q * 4 + r;
            if (node < n) {
                if (YL8)
                    ((unsigned char*)yl)[(size_t)node * PAD + ncol] = f2fp8(accl[t][r]);
                else
                    ((unsigned short*)yl)[(size_t)node * PAD + ncol] = f2bf(accl[t][r]);
                yr[(size_t)node * PAD + ncol] = f2bf(accr[t][r] + biasv[t]);
            }
        }
    }
}

// ---------------- aggregate: h = act(norm(mean_gather(yl) + yr)) ------------
// R16: software-pipelined col prefetch — next quad's col indices load while
// current quad's payload gathers are outstanding (8 loads in flight).
// PK: 0 = bf16 payload (uint4/row-chunk), 1 = fp8 payload (uint2/row-chunk).
template <int F, int ACT, int PK>
__global__ __launch_bounds__(256) void agg_kernel(
        const void* __restrict__ yl, const unsigned short* __restrict__ yr,
        const int* __restrict__ rowptr, const int* __restrict__ degv,
        const int* __restrict__ col,
        unsigned short* __restrict__ hout, float* __restrict__ fout, int n) {
    constexpr int G = F / 8;
    constexpr int NPW = 64 / G;
    const int lane = threadIdx.x & 63;
    const int wid = (blockIdx.x * blockDim.x + threadIdx.x) >> 6;
    const int g = lane / G, c = lane % G;
    const int node = wid * NPW + g;
    if (node >= n) return;

    const int beg = rowptr[node];
    const int dg  = degv[node];
    const int nmax = n - 1;

    float a0=0.f,a1=0.f,a2=0.f,a3=0.f,a4=0.f,a5=0.f,a6=0.f,a7=0.f;
    int i = 0;
    if (PK == 1) {
        const unsigned char* base = (const unsigned char*)yl + c * 8;
        auto accrow = [&](uint2 t) {
            const floatx2 p0 = __builtin_amdgcn_cvt_pk_f32_fp8((int)t.x, false);
            const floatx2 p1 = __builtin_amdgcn_cvt_pk_f32_fp8((int)t.x, true);
            const floatx2 p2 = __builtin_amdgcn_cvt_pk_f32_fp8((int)t.y, false);
            const floatx2 p3 = __builtin_amdgcn_cvt_pk_f32_fp8((int)t.y, true);
            a0 += p0.x; a1 += p0.y; a2 += p1.x; a3 += p1.y;
            a4 += p2.x; a5 += p2.y; a6 += p3.x; a7 += p3.y;
        };
        if (dg >= 4) {
            int c0 = col[beg], c1 = col[beg+1], c2 = col[beg+2], c3 = col[beg+3];
            for (; i + 8 <= dg; i += 4) {
                const int d0 = col[beg+i+4], d1 = col[beg+i+5];
                const int d2 = col[beg+i+6], d3 = col[beg+i+7];
                const uint2 t0 = *(const uint2*)(base + (size_t)min(c0,nmax) * F);
                const uint2 t1 = *(const uint2*)(base + (size_t)min(c1,nmax) * F);
                const uint2 t2 = *(const uint2*)(base + (size_t)min(c2,nmax) * F);
                const uint2 t3 = *(const uint2*)(base + (size_t)min(c3,nmax) * F);
                accrow(t0); accrow(t1); accrow(t2); accrow(t3);
                c0 = d0; c1 = d1; c2 = d2; c3 = d3;
            }
            const uint2 t0 = *(const uint2*)(base + (size_t)min(c0,nmax) * F);
            const uint2 t1 = *(const uint2*)(base + (size_t)min(c1,nmax) * F);
            const uint2 t2 = *(const uint2*)(base + (size_t)min(c2,nmax) * F);
            const uint2 t3 = *(const uint2*)(base + (size_t)min(c3,nmax) * F);
            accrow(t0); accrow(t1); accrow(t2); accrow(t3);
            i += 4;
        }
        for (; i < dg; ++i)
            accrow(*(const uint2*)(base + (size_t)min(col[beg+i],nmax) * F));
    } else {
        const unsigned short* base = (const unsigned short*)yl + c * 8;
        auto accrow4 = [&](uint4 t) {
            a0 += blo(t.x); a1 += bhi(t.x); a2 += blo(t.y); a3 += bhi(t.y);
            a4 += blo(t.z); a5 += bhi(t.z); a6 += blo(t.w); a7 += bhi(t.w);
        };
        if (dg >= 4) {
            int c0 = col[beg], c1 = col[beg+1], c2 = col[beg+2], c3 = col[beg+3];
            for (; i + 8 <= dg; i += 4) {
                const int d0 = col[beg+i+4], d1 = col[beg+i+5];
                const int d2 = col[beg+i+6], d3 = col[beg+i+7];
                const uint4 t0 = *(const uint4*)(base + (size_t)min(c0,nmax) * F);
                const uint4 t1 = *(const uint4*)(base + (size_t)min(c1,nmax) * F);
                const uint4 t2 = *(const uint4*)(base + (size_t)min(c2,nmax) * F);
                const uint4 t3 = *(const uint4*)(base + (size_t)min(c3,nmax) * F);
                accrow4(t0); accrow4(t1); accrow4(t2); accrow4(t3);
                c0 = d0; c1 = d1; c2 = d2; c3 = d3;
            }
            const uint4 t0 = *(const uint4*)(base + (size_t)min(c0,nmax) * F);
            const uint4 t1 = *(const uint4*)(base + (size_t)min(c1,nmax) * F);
            const uint4 t2 = *(const uint4*)(base + (size_t)min(c2,nmax) * F);
            const uint4 t3 = *(const uint4*)(base + (size_t)min(c3,nmax) * F);
            accrow4(t0); accrow4(t1); accrow4(t2); accrow4(t3);
            i += 4;
        }
        for (; i < dg; ++i)
            accrow4(*(const uint4*)(base + (size_t)min(col[beg+i],nmax) * F));
    }
    const float inv = (dg > 0) ? 1.f / (float)dg : 0.f;

    // yr residual: bf16, coalesced
    const uint4 rv = *(const uint4*)(yr + (size_t)node * F + c * 8);
    float o[8];
    o[0] = a0*inv + blo(rv.x); o[1] = a1*inv + bhi(rv.x);
    o[2] = a2*inv + blo(rv.y); o[3] = a3*inv + bhi(rv.y);
    o[4] = a4*inv + blo(rv.z); o[5] = a5*inv + bhi(rv.z);
    o[6] = a6*inv + blo(rv.w); o[7] = a7*inv + bhi(rv.w);

    float ss = 0.f;
#pragma unroll
    for (int j = 0; j < 8; ++j) ss += o[j] * o[j];
#pragma unroll
    for (int off = 1; off < G; off <<= 1) ss += __shfl_xor(ss, off);
    const float scale = 1.f / fmaxf(sqrtf(ss), 1e-12f);

    if (ACT == 1) {
        uint4 u;
        float h[8];
#pragma unroll
        for (int j = 0; j < 8; ++j) h[j] = fmaxf(o[j] * scale, 0.f);
        u.x = (unsigned)f2bf(h[0]) | ((unsigned)f2bf(h[1]) << 16);
        u.y = (unsigned)f2bf(h[2]) | ((unsigned)f2bf(h[3]) << 16);
        u.z = (unsigned)f2bf(h[4]) | ((unsigned)f2bf(h[5]) << 16);
        u.w = (unsigned)f2bf(h[6]) | ((unsigned)f2bf(h[7]) << 16);
        *(uint4*)(hout + (size_t)node * F + c * 8) = u;
    } else {
#pragma unroll
        for (int j = 0; j < 8; ++j) o[j] *= scale;
        const int cbase = c * 8;
        float m = -INFINITY;
#pragma unroll
        for (int j = 0; j < 8; ++j) if (cbase + j < 10) m = fmaxf(m, o[j]);
        m = fmaxf(m, __shfl_xor(m, 1));
        float s = 0.f;
#pragma unroll
        for (int j = 0; j < 8; ++j) if (cbase + j < 10) s += __expf(o[j] - m);
        s += __shfl_xor(s, 1);
        const float ls = logf(s);
#pragma unroll
        for (int j = 0; j < 8; ++j)
            if (cbase + j < 10) fout[(size_t)node * 10 + cbase + j] = o[j] - m - ls;
    }
}

extern "C" void kernel_launch(void* const* d_in, const int* in_sizes, int n_in,
                              void* d_out, int out_size, void* d_ws, size_t ws_size,
                              hipStream_t stream) {
    const float* x   = (const float*)d_in[0];
    const int*   ei  = (const int*)d_in[1];     // int64 in ref -> int32 on device
    const float* W1l = (const float*)d_in[2];
    const float* W1r = (const float*)d_in[3];
    const float* b1  = (const float*)d_in[4];
    const float* W2l = (const float*)d_in[5];
    const float* W2r = (const float*)d_in[6];
    const float* b2  = (const float*)d_in[7];
    const float* W3l = (const float*)d_in[8];
    const float* W3r = (const float*)d_in[9];
    const float* b3  = (const float*)d_in[10];
    float*       out = (float*)d_out;

    const int N = in_sizes[0] / 64;
    const int E = in_sizes[1] / 2;
    const int NBKT = (N + 511) >> 9;     // dst buckets of 512 nodes (<=256)
    const int NB   = (E + 4095) >> 12;   // 4096 edges per hist/scatter block

    auto align16 = [](size_t v) { return (v + 15) & ~(size_t)15; };
    char* ws = (char*)d_ws;
    size_t off = 0;
    int* rowptr  = (int*)(ws + off); off = align16(off + (size_t)N * 4);
    int* deg     = (int*)(ws + off); off = align16(off + (size_t)N * 4);
    int* colidx  = (int*)(ws + off); off = align16(off + (size_t)E * 4);
    unsigned* ebuf = (unsigned*)(ws + off); off = align16(off + (size_t)E * 4);
    int* bh      = (int*)(ws + off); off = align16(off + (size_t)NBKT * NB * 4);
    int* offsb   = (int*)(ws + off); off = align16(off + (size_t)NBKT * NB * 4);
    int* btot    = (int*)(ws + off); off = align16(off + (size_t)NBKT * 4);
    int* bbase   = (int*)(ws + off); off = align16(off + (size_t)(NBKT + 1) * 4);
    int* sctr    = (int*)(ws + off); off = align16(off + 16);
    unsigned char*  y1l = (unsigned char*)(ws + off);  off = align16(off + (size_t)N * 64);
    unsigned short* y1r = (unsigned short*)(ws + off); off = align16(off + (size_t)N * 64 * 2);
    unsigned short* h1  = (unsigned short*)(ws + off); off = align16(off + (size_t)N * 64 * 2);
    unsigned char*  y2l = (unsigned char*)(ws + off);  off = align16(off + (size_t)N * 32);
    unsigned short* y2r = (unsigned short*)(ws + off); off = align16(off + (size_t)N * 32 * 2);
    unsigned short* h2  = (unsigned short*)(ws + off); off = align16(off + (size_t)N * 32 * 2);
    unsigned short* y3l = (unsigned short*)(ws + off); off = align16(off + (size_t)N * 16 * 2);
    unsigned short* y3r = (unsigned short*)(ws + off); off = align16(off + (size_t)N * 16 * 2);
    (void)ws_size; (void)n_in; (void)out_size;

    const int ntiles = (N + 15) / 16;                  // MFMA node tiles
    const int tblocks = (ntiles * 64 + 255) / 256;     // 4 waves/block (t1)

    // ---- CSR build; transform1 overlapped with scatter (independent work)
    hist_kernel<<<NB, 256, 0, stream>>>(ei, bh, sctr, E, NB, NBKT);
    bscan_kernel<<<(NBKT + 3) / 4, 256, 0, stream>>>(bh, offsb, btot, bbase, sctr, NB, NBKT);
    scatter_t1_kernel<64, 64, 64, true, true><<<NB + tblocks, 256, 0, stream>>>(
        ei, offsb, bbase, ebuf, E, NB, NBKT,
        x, W1l, W1r, b1, y1l, y1r, N);
    bucket_csr_kernel<<<NBKT, 1024, 0, stream>>>(ebuf, bbase, rowptr, deg, colidx, N, E);

    // layer 1 (fp8 gather payload)
    agg_kernel<64, 1, 1><<<(N + 31) / 32, 256, 0, stream>>>(
        y1l, y1r, rowptr, deg, colidx, h1, nullptr, N);
    // layer 2 (fp8 gather payload)
    transform_kernel<64, 32, 32, false, true><<<tblocks, 256, 0, stream>>>(
        h1, W2l, W2r, b2, y2l, y2r, N);
    agg_kernel<32, 1, 1><<<(N + 63) / 64, 256, 0, stream>>>(
        y2l, y2r, rowptr, deg, colidx, h2, nullptr, N);
    // layer 3 (bf16 payload, L2-resident)
    transform_kernel<32, 10, 16, false, false><<<tblocks, 256, 0, stream>>>(
        h2, W3l, W3r, b3, y3l, y3r, N);
    agg_kernel<16, 2, 0><<<(N + 127) / 128, 256, 0, stream>>>(
        y3l, y3r, rowptr, deg, colidx, nullptr, out, N);
}